// Round 2
// baseline (255.464 us; speedup 1.0000x reference)
//
#include <hip/hip_runtime.h>
#include <stdint.h>

typedef unsigned short u16;
typedef unsigned int u32;
typedef __bf16 bf16x8 __attribute__((ext_vector_type(8)));
typedef float f32x4 __attribute__((ext_vector_type(4)));

#define MFMA16 __builtin_amdgcn_mfma_f32_16x16x32_bf16

static __device__ __forceinline__ u16 f2bf(float f) {
  union { float f; u32 u; } v; v.f = f;
  u32 r = v.u + 0x7FFFu + ((v.u >> 16) & 1u);
  return (u16)(r >> 16);
}
static __device__ __forceinline__ float bf2f(u16 b) {
  union { float f; u32 u; } v; v.u = ((u32)b) << 16;
  return v.f;
}
static __device__ __forceinline__ void load_lds16(const void* g, void* l) {
  __builtin_amdgcn_global_load_lds(
      (const __attribute__((address_space(1))) void*)g,
      (__attribute__((address_space(3))) void*)l, 16, 0, 0);
}

// ---------------- fp32 -> bf16 convert (vectorized) ----------------
__global__ __launch_bounds__(256) void cvt_bf16(const float* __restrict__ in,
                                                u16* __restrict__ out, int n4) {
  int i = blockIdx.x * 256 + threadIdx.x;
  if (i >= n4) return;
  float4 v = reinterpret_cast<const float4*>(in)[i];
  uint2 r;
  r.x = (u32)f2bf(v.x) | ((u32)f2bf(v.y) << 16);
  r.y = (u32)f2bf(v.z) | ((u32)f2bf(v.w) << 16);
  reinterpret_cast<uint2*>(out)[i] = r;
}

// ---------------- bf16 GEMM, C[M][N] = A[M][K] @ B[N][K]^T ----------------
// m97 structure: 128x128 tile, 4 waves (64x64 each), BK=32, global_load_lds w16.
template <bool OUT_BF16>
__global__ __launch_bounds__(256, 2) void gemm_bt(const u16* __restrict__ A,
                                                  const u16* __restrict__ B,
                                                  void* __restrict__ Cv,
                                                  int M, int N, int K) {
  __shared__ u16 As[128 * 32];
  __shared__ u16 Bs[128 * 32];
  const int t = threadIdx.x;
  const int w = t >> 6, lane = t & 63;
  const int brow = blockIdx.y * 128, bcol = blockIdx.x * 128;
  const int wr = (w >> 1) * 64, wc = (w & 1) * 64;

  f32x4 acc[4][4];
#pragma unroll
  for (int i = 0; i < 4; ++i)
#pragma unroll
    for (int j = 0; j < 4; ++j) acc[i][j] = (f32x4){0.f, 0.f, 0.f, 0.f};

  const int srow = w * 16 + (lane >> 2);   // staging row within 64-row half
  const int scol = (lane & 3) * 8;         // staging col (8 bf16 = 16B)
  const u16* ga = A + (size_t)(brow + srow) * K + scol;
  const u16* gb = B + (size_t)(bcol + srow) * K + scol;
  const size_t rstep = (size_t)64 * K;
  u16* ldsA = As + w * 512;                // wave-uniform LDS dest (bytes w*1024)
  u16* ldsB = Bs + w * 512;

  const int lc = lane & 15, lg = lane >> 4;
  const int kg = lg * 8;

  const int nk = K >> 5;
  for (int kt = 0; kt < nk; ++kt) {
    __syncthreads();
    load_lds16(ga, ldsA);
    load_lds16(ga + rstep, (char*)ldsA + 4096);
    load_lds16(gb, ldsB);
    load_lds16(gb + rstep, (char*)ldsB + 4096);
    ga += 32; gb += 32;
    asm volatile("s_waitcnt vmcnt(0)" ::: "memory");
    __syncthreads();
    bf16x8 af[4], bfr[4];
#pragma unroll
    for (int i = 0; i < 4; ++i)
      af[i] = *reinterpret_cast<const bf16x8*>(As + (wr + i * 16 + lc) * 32 + kg);
#pragma unroll
    for (int j = 0; j < 4; ++j)
      bfr[j] = *reinterpret_cast<const bf16x8*>(Bs + (wc + j * 16 + lc) * 32 + kg);
#pragma unroll
    for (int i = 0; i < 4; ++i)
#pragma unroll
      for (int j = 0; j < 4; ++j)
        acc[i][j] = MFMA16(af[i], bfr[j], acc[i][j], 0, 0, 0);
  }

  const int r0 = lg * 4;
#pragma unroll
  for (int i = 0; i < 4; ++i)
#pragma unroll
    for (int j = 0; j < 4; ++j)
#pragma unroll
      for (int r = 0; r < 4; ++r) {
        const int m = brow + wr + i * 16 + r0 + r;
        const int n = bcol + wc + j * 16 + lc;
        if constexpr (OUT_BF16)
          ((u16*)Cv)[(size_t)m * N + n] = f2bf(acc[i][j][r]);
        else
          ((float*)Cv)[(size_t)m * N + n] = acc[i][j][r];
      }
}

// ---------------- RoPE trig table: [s][pair] -> (cos, sin) ----------------
__global__ __launch_bounds__(256) void build_trig(const int* __restrict__ pos,
                                                  float2* __restrict__ tab) {
  int i = blockIdx.x * 256 + threadIdx.x;  // 2048*32 = 65536
  int s = i >> 5, p = i & 31;
  float inv = powf(10000.0f, -(float)p * (1.0f / 32.0f));
  float fr = (float)pos[s] * inv;
  float sn, cs;
  sincosf(fr, &sn, &cs);
  tab[i] = make_float2(cs, sn);
}

// ---------------- RoPE + repack q,k -> [B*H][S][64] (q pre-scaled 0.125) ----
__global__ __launch_bounds__(256) void rope_repack(const u16* __restrict__ qkv,
                                                   const float2* __restrict__ tab,
                                                   u16* __restrict__ Qro,
                                                   u16* __restrict__ Kro) {
  int idx = blockIdx.x * 256 + threadIdx.x;  // 4096*16*32 = 2M threads
  int p = idx & 31;
  int h = (idx >> 5) & 15;
  int m = idx >> 9;
  int b = m >> 11, s = m & 2047;
  const u32* row = reinterpret_cast<const u32*>(qkv + (size_t)m * 3072);
  u32 qp = row[h * 32 + p];
  u32 kp = row[512 + h * 32 + p];
  float2 cssn = tab[s * 32 + p];
  float cs = cssn.x, sn = cssn.y;
  float qe = bf2f((u16)(qp & 0xffffu)), qo = bf2f((u16)(qp >> 16));
  float ke = bf2f((u16)(kp & 0xffffu)), ko = bf2f((u16)(kp >> 16));
  float qre = (qe * cs - qo * sn) * 0.125f;
  float qro_ = (qe * sn + qo * cs) * 0.125f;
  float kre = ke * cs - ko * sn;
  float kro_ = ke * sn + ko * cs;
  size_t o = ((size_t)(b * 16 + h) * 2048 + s) * 32 + p;
  reinterpret_cast<u32*>(Qro)[o] = (u32)f2bf(qre) | ((u32)f2bf(qro_) << 16);
  reinterpret_cast<u32*>(Kro)[o] = (u32)f2bf(kre) | ((u32)f2bf(kro_) << 16);
}

// ---------------- V -> V^T   ([B*H][S][64] slice of qkv -> [B*H][64][S]) ----
__global__ __launch_bounds__(256) void v_transpose(const u16* __restrict__ qkv,
                                                   u16* __restrict__ VT) {
  const int bh = blockIdx.y;
  const int s0 = blockIdx.x * 64;
  const int b = bh >> 4, h = bh & 15;
  __shared__ u16 tile[64][72];  // +8 pad
  const int t = threadIdx.x;
#pragma unroll
  for (int c = 0; c < 2; ++c) {
    int r = c * 32 + (t >> 3);
    int d = (t & 7) * 8;
    const u16* src = qkv + (size_t)(b * 2048 + s0 + r) * 3072 + 2048 + h * 64 + d;
    *reinterpret_cast<uint4*>(&tile[r][d]) = *reinterpret_cast<const uint4*>(src);
  }
  __syncthreads();
#pragma unroll
  for (int c = 0; c < 2; ++c) {
    int dd = c * 32 + (t >> 3);
    int sg = (t & 7) * 8;
    u16 tmp[8];
#pragma unroll
    for (int jj = 0; jj < 8; ++jj) tmp[jj] = tile[sg + jj][dd];
    *reinterpret_cast<uint4*>(VT + ((size_t)bh * 64 + dd) * 2048 + s0 + sg) =
        *reinterpret_cast<const uint4*>(tmp);
  }
}

// ---------------- flash attention (non-causal), per (b,h) ----------------
// 4 waves x 32 q-rows = 128 q/block; KVBLK=64; K/V tiles XOR-swizzled
// (linear LDS dest + swizzled global source + swizzled reads).
__global__ __launch_bounds__(256, 2) void attn_fwd(const u16* __restrict__ Q,
                                                   const u16* __restrict__ Kg,
                                                   const u16* __restrict__ VTg,
                                                   u16* __restrict__ O) {
  constexpr int S = 2048;
  __shared__ u16 Kl[64 * 64];
  __shared__ u16 Vl[64 * 64];
  __shared__ u16 Pl[4][32 * 64];
  const int t = threadIdx.x, w = t >> 6, lane = t & 63;
  const int bh = blockIdx.y;
  const int q0 = blockIdx.x * 128 + w * 32;
  const size_t base = (size_t)bh * S * 64;
  const int lc = lane & 15, lg = lane >> 4;

  bf16x8 qf[2][2];
#pragma unroll
  for (int i = 0; i < 2; ++i)
#pragma unroll
    for (int ks = 0; ks < 2; ++ks)
      qf[i][ks] = *reinterpret_cast<const bf16x8*>(
          Q + base + (size_t)(q0 + i * 16 + lc) * 64 + ks * 32 + lg * 8);

  f32x4 Oa[2][4];
  float mrow[2][4], lsum[2][4];
#pragma unroll
  for (int i = 0; i < 2; ++i) {
#pragma unroll
    for (int j = 0; j < 4; ++j) Oa[i][j] = (f32x4){0.f, 0.f, 0.f, 0.f};
#pragma unroll
    for (int r = 0; r < 4; ++r) { mrow[i][r] = -__builtin_inff(); lsum[i][r] = 0.f; }
  }

  u16* Pw = Pl[w];
  for (int kt = 0; kt < S / 64; ++kt) {
    __syncthreads();
#pragma unroll
    for (int c = 0; c < 2; ++c) {
      const int o = c * 4096 + w * 1024 + lane * 16;
      const int row = o >> 7;
      const int swz = (o & 127) ^ ((row & 7) << 4);
      load_lds16((const char*)(Kg + base + kt * 4096) + row * 128 + swz,
                 (char*)Kl + c * 4096 + w * 1024);
      load_lds16((const char*)(VTg + base) + (size_t)row * (S * 2) + kt * 128 + swz,
                 (char*)Vl + c * 4096 + w * 1024);
    }
    asm volatile("s_waitcnt vmcnt(0)" ::: "memory");
    __syncthreads();

    // QK^T  (scale pre-folded into Q)
    f32x4 Sa[2][4];
#pragma unroll
    for (int i = 0; i < 2; ++i)
#pragma unroll
      for (int j = 0; j < 4; ++j) Sa[i][j] = (f32x4){0.f, 0.f, 0.f, 0.f};
#pragma unroll
    for (int ks = 0; ks < 2; ++ks) {
      bf16x8 kf[4];
#pragma unroll
      for (int j = 0; j < 4; ++j) {
        int kv = j * 16 + lc;
        int a = (kv * 128 + ks * 64 + lg * 16) ^ ((kv & 7) << 4);
        kf[j] = *reinterpret_cast<const bf16x8*>((const char*)Kl + a);
      }
#pragma unroll
      for (int i = 0; i < 2; ++i)
#pragma unroll
        for (int j = 0; j < 4; ++j)
          Sa[i][j] = MFMA16(qf[i][ks], kf[j], Sa[i][j], 0, 0, 0);
    }

    // online softmax (rows live in 16-lane col groups -> shfl_xor 1,2,4,8)
    float pm[2][4];
#pragma unroll
    for (int i = 0; i < 2; ++i)
#pragma unroll
      for (int r = 0; r < 4; ++r)
        pm[i][r] = fmaxf(fmaxf(Sa[i][0][r], Sa[i][1][r]),
                         fmaxf(Sa[i][2][r], Sa[i][3][r]));
#pragma unroll
    for (int msk = 1; msk < 16; msk <<= 1)
#pragma unroll
      for (int i = 0; i < 2; ++i)
#pragma unroll
        for (int r = 0; r < 4; ++r)
          pm[i][r] = fmaxf(pm[i][r], __shfl_xor(pm[i][r], msk));

    float sc[2][4];
#pragma unroll
    for (int i = 0; i < 2; ++i)
#pragma unroll
      for (int r = 0; r < 4; ++r) {
        float mn = fmaxf(mrow[i][r], pm[i][r]);
        sc[i][r] = __expf(mrow[i][r] - mn);
        mrow[i][r] = mn;
      }

    float pv[2][4][4];
    float rs[2][4];
#pragma unroll
    for (int i = 0; i < 2; ++i)
#pragma unroll
      for (int r = 0; r < 4; ++r) rs[i][r] = 0.f;
#pragma unroll
    for (int i = 0; i < 2; ++i)
#pragma unroll
      for (int j = 0; j < 4; ++j)
#pragma unroll
        for (int r = 0; r < 4; ++r) {
          float e = __expf(Sa[i][j][r] - mrow[i][r]);
          pv[i][j][r] = e;
          rs[i][r] += e;
        }
#pragma unroll
    for (int msk = 1; msk < 16; msk <<= 1)
#pragma unroll
      for (int i = 0; i < 2; ++i)
#pragma unroll
        for (int r = 0; r < 4; ++r)
          rs[i][r] += __shfl_xor(rs[i][r], msk);
#pragma unroll
    for (int i = 0; i < 2; ++i)
#pragma unroll
      for (int r = 0; r < 4; ++r)
        lsum[i][r] = lsum[i][r] * sc[i][r] + rs[i][r];
#pragma unroll
    for (int i = 0; i < 2; ++i)
#pragma unroll
      for (int j = 0; j < 4; ++j)
#pragma unroll
        for (int r = 0; r < 4; ++r) Oa[i][j][r] *= sc[i][r];

    // P -> LDS (per-wave, swizzled) for the PV A-operand re-layout
#pragma unroll
    for (int i = 0; i < 2; ++i)
#pragma unroll
      for (int j = 0; j < 4; ++j)
#pragma unroll
        for (int r = 0; r < 4; ++r) {
          int qloc = i * 16 + lg * 4 + r;
          int kv = j * 16 + lc;
          int a = (qloc * 128 + kv * 2) ^ ((qloc & 7) << 4);
          *(u16*)((char*)Pw + a) = f2bf(pv[i][j][r]);
        }
    asm volatile("s_waitcnt lgkmcnt(0)" ::: "memory");
    __builtin_amdgcn_sched_barrier(0);

    // PV
#pragma unroll
    for (int ks = 0; ks < 2; ++ks) {
      bf16x8 pa[2], vf[4];
#pragma unroll
      for (int i = 0; i < 2; ++i) {
        int qloc = i * 16 + lc;
        int a = (qloc * 128 + ks * 64 + lg * 16) ^ ((qloc & 7) << 4);
        pa[i] = *reinterpret_cast<const bf16x8*>((const char*)Pw + a);
      }
#pragma unroll
      for (int j = 0; j < 4; ++j) {
        int d = j * 16 + lc;
        int a = (d * 128 + ks * 64 + lg * 16) ^ ((d & 7) << 4);
        vf[j] = *reinterpret_cast<const bf16x8*>((const char*)Vl + a);
      }
#pragma unroll
      for (int i = 0; i < 2; ++i)
#pragma unroll
        for (int j = 0; j < 4; ++j)
          Oa[i][j] = MFMA16(pa[i], vf[j], Oa[i][j], 0, 0, 0);
    }
  }

  const int b = bh >> 4, h = bh & 15;
#pragma unroll
  for (int i = 0; i < 2; ++i)
#pragma unroll
    for (int j = 0; j < 4; ++j)
#pragma unroll
      for (int r = 0; r < 4; ++r) {
        int s = q0 + i * 16 + lg * 4 + r;
        float v = Oa[i][j][r] / lsum[i][r];
        O[(size_t)(b * S + s) * 1024 + h * 64 + j * 16 + lc] = f2bf(v);
      }
}

extern "C" void kernel_launch(void* const* d_in, const int* in_sizes, int n_in,
                              void* d_out, int out_size, void* d_ws, size_t ws_size,
                              hipStream_t stream) {
  (void)in_sizes; (void)n_in; (void)out_size; (void)ws_size;
  const float* x = (const float*)d_in[0];
  const float* wqkv = (const float*)d_in[1];
  const float* wout = (const float*)d_in[2];
  const int* pos = (const int*)d_in[3];
  float* out = (float*)d_out;

  char* ws = (char*)d_ws;
  u16* xb     = (u16*)(ws);             // 8 MB   x bf16 [4096][1024]
  u16* wqkvb  = (u16*)(ws + 8388608);   // 6 MB   Wqkv bf16 [3072][1024]
  u16* woutb  = (u16*)(ws + 14680064);  // 2 MB   Wout bf16 [1024][1024]
  u16* qkvb   = (u16*)(ws + 16777216);  // 24 MB  qkv bf16 [4096][3072]
  u16* qro    = (u16*)(ws + 41943040);  // 8 MB   q roped*0.125 [BH][S][64]
  u16* kro    = (u16*)(ws + 50331648);  // 8 MB   k roped [BH][S][64]
  u16* vt     = (u16*)(ws + 58720256);  // 8 MB   v^T [BH][64][S]
  u16* attno  = (u16*)(ws + 67108864);  // 8 MB   attn out bf16 [4096][1024]
  float2* tab = (float2*)(ws + 75497472); // 512 KB trig table

  cvt_bf16<<<4096, 256, 0, stream>>>(x, xb, 1048576);
  cvt_bf16<<<3072, 256, 0, stream>>>(wqkv, wqkvb, 786432);
  cvt_bf16<<<1024, 256, 0, stream>>>(wout, woutb, 262144);
  build_trig<<<256, 256, 0, stream>>>(pos, tab);
  gemm_bt<true><<<dim3(24, 32), 256, 0, stream>>>(xb, wqkvb, qkvb, 4096, 3072, 1024);
  rope_repack<<<8192, 256, 0, stream>>>(qkvb, tab, qro, kro);
  v_transpose<<<dim3(32, 32), 256, 0, stream>>>(qkvb, vt);
  attn_fwd<<<dim3(16, 32), 256, 0, stream>>>(qro, kro, vt, attno);
  gemm_bt<false><<<dim3(8, 32), 256, 0, stream>>>(attno, woutb, out, 4096, 1024, 1024);
}

// Round 3
// 231.477 us; speedup vs baseline: 1.1036x; 1.1036x over previous
//
#include <hip/hip_runtime.h>
#include <stdint.h>

typedef unsigned short u16;
typedef unsigned int u32;
typedef __bf16 bf16x8 __attribute__((ext_vector_type(8)));
typedef float f32x4 __attribute__((ext_vector_type(4)));
typedef float f32x16 __attribute__((ext_vector_type(16)));

#define MFMA16 __builtin_amdgcn_mfma_f32_16x16x32_bf16
#define MFMA32 __builtin_amdgcn_mfma_f32_32x32x16_bf16

static __device__ __forceinline__ u16 f2bf(float f) {
  union { float f; u32 u; } v; v.f = f;
  u32 r = v.u + 0x7FFFu + ((v.u >> 16) & 1u);
  return (u16)(r >> 16);
}
static __device__ __forceinline__ float bf2f(u16 b) {
  union { float f; u32 u; } v; v.u = ((u32)b) << 16;
  return v.f;
}
static __device__ __forceinline__ void load_lds16(const void* g, void* l) {
  __builtin_amdgcn_global_load_lds(
      (const __attribute__((address_space(1))) void*)g,
      (__attribute__((address_space(3))) void*)l, 16, 0, 0);
}

// ---------------- fp32 -> bf16 convert (vectorized) ----------------
__global__ __launch_bounds__(256) void cvt_bf16(const float* __restrict__ in,
                                                u16* __restrict__ out, int n4) {
  int i = blockIdx.x * 256 + threadIdx.x;
  if (i >= n4) return;
  float4 v = reinterpret_cast<const float4*>(in)[i];
  uint2 r;
  r.x = (u32)f2bf(v.x) | ((u32)f2bf(v.y) << 16);
  r.y = (u32)f2bf(v.z) | ((u32)f2bf(v.w) << 16);
  reinterpret_cast<uint2*>(out)[i] = r;
}

// ---------------- bf16 GEMM, C[M][N] = A[M][K] @ B[N][K]^T ----------------
template <bool OUT_BF16>
__global__ __launch_bounds__(256, 2) void gemm_bt(const u16* __restrict__ A,
                                                  const u16* __restrict__ B,
                                                  void* __restrict__ Cv,
                                                  int M, int N, int K) {
  __shared__ u16 As[128 * 32];
  __shared__ u16 Bs[128 * 32];
  const int t = threadIdx.x;
  const int w = t >> 6, lane = t & 63;
  const int brow = blockIdx.y * 128, bcol = blockIdx.x * 128;
  const int wr = (w >> 1) * 64, wc = (w & 1) * 64;

  f32x4 acc[4][4];
#pragma unroll
  for (int i = 0; i < 4; ++i)
#pragma unroll
    for (int j = 0; j < 4; ++j) acc[i][j] = (f32x4){0.f, 0.f, 0.f, 0.f};

  const int srow = w * 16 + (lane >> 2);
  const int scol = (lane & 3) * 8;
  const u16* ga = A + (size_t)(brow + srow) * K + scol;
  const u16* gb = B + (size_t)(bcol + srow) * K + scol;
  const size_t rstep = (size_t)64 * K;
  u16* ldsA = As + w * 512;
  u16* ldsB = Bs + w * 512;

  const int lc = lane & 15, lg = lane >> 4;
  const int kg = lg * 8;

  const int nk = K >> 5;
  for (int kt = 0; kt < nk; ++kt) {
    __syncthreads();
    load_lds16(ga, ldsA);
    load_lds16(ga + rstep, (char*)ldsA + 4096);
    load_lds16(gb, ldsB);
    load_lds16(gb + rstep, (char*)ldsB + 4096);
    ga += 32; gb += 32;
    asm volatile("s_waitcnt vmcnt(0)" ::: "memory");
    __syncthreads();
    bf16x8 af[4], bfr[4];
#pragma unroll
    for (int i = 0; i < 4; ++i)
      af[i] = *reinterpret_cast<const bf16x8*>(As + (wr + i * 16 + lc) * 32 + kg);
#pragma unroll
    for (int j = 0; j < 4; ++j)
      bfr[j] = *reinterpret_cast<const bf16x8*>(Bs + (wc + j * 16 + lc) * 32 + kg);
#pragma unroll
    for (int i = 0; i < 4; ++i)
#pragma unroll
      for (int j = 0; j < 4; ++j)
        acc[i][j] = MFMA16(af[i], bfr[j], acc[i][j], 0, 0, 0);
  }

  const int r0 = lg * 4;
#pragma unroll
  for (int i = 0; i < 4; ++i)
#pragma unroll
    for (int j = 0; j < 4; ++j)
#pragma unroll
      for (int r = 0; r < 4; ++r) {
        const int m = brow + wr + i * 16 + r0 + r;
        const int n = bcol + wc + j * 16 + lc;
        if constexpr (OUT_BF16)
          ((u16*)Cv)[(size_t)m * N + n] = f2bf(acc[i][j][r]);
        else
          ((float*)Cv)[(size_t)m * N + n] = acc[i][j][r];
      }
}

// ---------------- RoPE trig table: [s][pair] -> (cos, sin) ----------------
__global__ __launch_bounds__(256) void build_trig(const int* __restrict__ pos,
                                                  float2* __restrict__ tab) {
  int i = blockIdx.x * 256 + threadIdx.x;
  int s = i >> 5, p = i & 31;
  float inv = powf(10000.0f, -(float)p * (1.0f / 32.0f));
  float fr = (float)pos[s] * inv;
  float sn, cs;
  sincosf(fr, &sn, &cs);
  tab[i] = make_float2(cs, sn);
}

// ------- RoPE + repack q,k -> [B*H][S][64]  (q pre-scaled 0.125*log2e) -----
__global__ __launch_bounds__(256) void rope_repack(const u16* __restrict__ qkv,
                                                   const float2* __restrict__ tab,
                                                   u16* __restrict__ Qro,
                                                   u16* __restrict__ Kro) {
  int idx = blockIdx.x * 256 + threadIdx.x;
  int p = idx & 31;
  int h = (idx >> 5) & 15;
  int m = idx >> 9;
  int b = m >> 11, s = m & 2047;
  const u32* row = reinterpret_cast<const u32*>(qkv + (size_t)m * 3072);
  u32 qp = row[h * 32 + p];
  u32 kp = row[512 + h * 32 + p];
  float2 cssn = tab[s * 32 + p];
  float cs = cssn.x, sn = cssn.y;
  float qe = bf2f((u16)(qp & 0xffffu)), qo = bf2f((u16)(qp >> 16));
  float ke = bf2f((u16)(kp & 0xffffu)), ko = bf2f((u16)(kp >> 16));
  // 0.125 (1/sqrt(64)) * log2(e): attention uses exp2 directly
  const float QS = 0.18033688011112042f;
  float qre = (qe * cs - qo * sn) * QS;
  float qro_ = (qe * sn + qo * cs) * QS;
  float kre = ke * cs - ko * sn;
  float kro_ = ke * sn + ko * cs;
  size_t o = ((size_t)(b * 16 + h) * 2048 + s) * 32 + p;
  reinterpret_cast<u32*>(Qro)[o] = (u32)f2bf(qre) | ((u32)f2bf(qro_) << 16);
  reinterpret_cast<u32*>(Kro)[o] = (u32)f2bf(kre) | ((u32)f2bf(kro_) << 16);
}

// ---------------- V -> V^T   ([B*H][S][64] slice of qkv -> [B*H][64][S]) ----
__global__ __launch_bounds__(256) void v_transpose(const u16* __restrict__ qkv,
                                                   u16* __restrict__ VT) {
  const int bh = blockIdx.y;
  const int s0 = blockIdx.x * 64;
  const int b = bh >> 4, h = bh & 15;
  __shared__ u16 tile[64][72];
  const int t = threadIdx.x;
#pragma unroll
  for (int c = 0; c < 2; ++c) {
    int r = c * 32 + (t >> 3);
    int d = (t & 7) * 8;
    const u16* src = qkv + (size_t)(b * 2048 + s0 + r) * 3072 + 2048 + h * 64 + d;
    *reinterpret_cast<uint4*>(&tile[r][d]) = *reinterpret_cast<const uint4*>(src);
  }
  __syncthreads();
#pragma unroll
  for (int c = 0; c < 2; ++c) {
    int dd = c * 32 + (t >> 3);
    int sg = (t & 7) * 8;
    u16 tmp[8];
#pragma unroll
    for (int jj = 0; jj < 8; ++jj) tmp[jj] = tile[sg + jj][dd];
    *reinterpret_cast<uint4*>(VT + ((size_t)bh * 64 + dd) * 2048 + s0 + sg) =
        *reinterpret_cast<const uint4*>(tmp);
  }
}

// ======== flash attention, swapped-operand 32x32 structure ========
// Per wave: 32 q rows. QK^T = mfma(K, Q) -> lane owns q-col, 32 P values in
// regs. In-register softmax (chain + shfl_xor(32)), defer-max THR=6 (exp2
// domain), P->bf16 via cvt_pk + permlane32_swap, PV = mfma(V^T, P) -> O^T.
// K/V staged via global_load_lds w16, XOR-swizzled source, 3-buffer pipeline
// with counted vmcnt(4) + raw s_barrier (one barrier per KV tile).
__global__ __launch_bounds__(256) void attn_fwd2(const u16* __restrict__ Q,
                                                 const u16* __restrict__ Kg,
                                                 const u16* __restrict__ VTg,
                                                 u16* __restrict__ O) {
  constexpr int S = 2048, NT = 32;
  __shared__ char lds[3][16384];  // [buf][ K 64x64 bf16 | V^T 64x64 bf16 ]
  const int t = threadIdx.x, wv = t >> 6, lane = t & 63;
  const int bid = blockIdx.x;
  // XCD grouping: 4 bh per XCD (K/V 2MB -> fits 4MB L2)
  const int slot = bid >> 3;
  const int bh = (bid & 7) * 4 + (slot >> 4);
  const int qb = slot & 15;
  const int b = bh >> 4, h = bh & 15;
  const int q0 = qb * 128 + wv * 32;
  const size_t kbase = (size_t)bh * (S * 64);
  const int l31 = lane & 31, hi = lane >> 5;

  // Q B-frags: lane holds Q[q0+l31][ds*16 + hi*8 + e]
  bf16x8 qf[4];
  {
    const u16* qp = Q + kbase + (size_t)(q0 + l31) * 64 + hi * 8;
#pragma unroll
    for (int d = 0; d < 4; ++d)
      qf[d] = *reinterpret_cast<const bf16x8*>(qp + d * 16);
  }

  f32x16 Oacc[2];
#pragma unroll
  for (int i = 0; i < 2; ++i)
#pragma unroll
    for (int r = 0; r < 16; ++r) Oacc[i][r] = 0.f;
  float m = -__builtin_inff(), lsum = 0.f;

  const char* gk0 = (const char*)(Kg + kbase);
  const char* gv0 = (const char*)(VTg + kbase);

#define STAGE(KT, BUF)                                                         \
  {                                                                            \
    char* lk_ = lds[BUF];                                                      \
    const char* gk_ = gk0 + (size_t)(KT) * 8192;                               \
    _Pragma("unroll") for (int c_ = 0; c_ < 2; ++c_) {                         \
      int o_ = (c_ * 256 + t) * 16;                                            \
      int row_ = o_ >> 7, colb_ = o_ & 127;                                    \
      int swz_ = colb_ ^ ((row_ & 7) << 4);                                    \
      load_lds16(gk_ + row_ * 128 + swz_, lk_ + o_);                           \
      load_lds16(gv0 + (size_t)row_ * 4096 + (KT) * 128 + swz_,                \
                 lk_ + 8192 + o_);                                             \
    }                                                                          \
  }

  STAGE(0, 0)
  STAGE(1, 1)
  asm volatile("s_waitcnt vmcnt(4)" ::: "memory");
  __builtin_amdgcn_s_barrier();

  int cur = 0;
  for (int kt = 0; kt < NT; ++kt) {
    const int nxt = kt + 2 < NT ? kt + 2 : NT - 1;
    const int nbuf = cur + 2 >= 3 ? cur - 1 : cur + 2;
    STAGE(nxt, nbuf)
    const char* lk = lds[cur];
    const char* lv = lds[cur] + 8192;

    // ---- QK^T (swapped): Sa[kvt] = S^T[kv][q], q = l31, kv = pattern ----
    f32x16 Sa[2];
#pragma unroll
    for (int i = 0; i < 2; ++i)
#pragma unroll
      for (int r = 0; r < 16; ++r) Sa[i][r] = 0.f;
#pragma unroll
    for (int d = 0; d < 4; ++d) {
#pragma unroll
      for (int kvt = 0; kvt < 2; ++kvt) {
        int kv = kvt * 32 + l31;
        int a = (kv * 128 + d * 32 + hi * 16) ^ ((kv & 7) << 4);
        bf16x8 kf = *reinterpret_cast<const bf16x8*>(lk + a);
        Sa[kvt] = MFMA32(kf, qf[d], Sa[kvt], 0, 0, 0);
      }
    }

    // ---- online softmax, in-register (exp2 domain) ----
    float pmax = Sa[0][0];
#pragma unroll
    for (int r = 1; r < 16; ++r) pmax = fmaxf(pmax, Sa[0][r]);
#pragma unroll
    for (int r = 0; r < 16; ++r) pmax = fmaxf(pmax, Sa[1][r]);
    pmax = fmaxf(pmax, __shfl_xor(pmax, 32));

    if (__any(pmax > m + 6.0f)) {  // defer-max: P bounded by 2^6
      float mn = fmaxf(m, pmax);
      float sc = exp2f(m - mn);
      m = mn;
      lsum *= sc;
#pragma unroll
      for (int i = 0; i < 2; ++i)
#pragma unroll
        for (int r = 0; r < 16; ++r) Oacc[i][r] *= sc;
    }

    float rs = 0.f;
#pragma unroll
    for (int kvt = 0; kvt < 2; ++kvt)
#pragma unroll
      for (int r = 0; r < 16; ++r) {
        float p = exp2f(Sa[kvt][r] - m);
        Sa[kvt][r] = p;
        rs += p;
      }
    rs += __shfl_xor(rs, 32);
    lsum += rs;

    // ---- P -> bf16 B-frags (cvt_pk + permlane32_swap) ----
    bf16x8 pfrag[4];
#pragma unroll
    for (int kvt = 0; kvt < 2; ++kvt)
#pragma unroll
      for (int s1 = 0; s1 < 2; ++s1) {
        u32 X0, X1, Y0, Y1;
        const int c0 = s1 * 8, c1 = c0 + 4;
        asm("v_cvt_pk_bf16_f32 %0, %1, %2"
            : "=v"(X0) : "v"(Sa[kvt][c0 + 0]), "v"(Sa[kvt][c0 + 1]));
        asm("v_cvt_pk_bf16_f32 %0, %1, %2"
            : "=v"(X1) : "v"(Sa[kvt][c0 + 2]), "v"(Sa[kvt][c0 + 3]));
        asm("v_cvt_pk_bf16_f32 %0, %1, %2"
            : "=v"(Y0) : "v"(Sa[kvt][c1 + 0]), "v"(Sa[kvt][c1 + 1]));
        asm("v_cvt_pk_bf16_f32 %0, %1, %2"
            : "=v"(Y1) : "v"(Sa[kvt][c1 + 2]), "v"(Sa[kvt][c1 + 3]));
        asm("v_permlane32_swap_b32 %0, %1" : "+v"(X0), "+v"(Y0));
        asm("v_permlane32_swap_b32 %0, %1" : "+v"(X1), "+v"(Y1));
        union { u32 w[4]; bf16x8 v; } u;
        u.w[0] = X0; u.w[1] = X1; u.w[2] = Y0; u.w[3] = Y1;
        pfrag[kvt * 2 + s1] = u.v;
      }

    // ---- PV (swapped): Oacc[dt] += mfma(V^T-frag, P-frag) -> O^T ----
#pragma unroll
    for (int s = 0; s < 4; ++s) {
#pragma unroll
      for (int dt = 0; dt < 2; ++dt) {
        int d = dt * 32 + l31;
        int a = (d * 128 + s * 32 + hi * 16) ^ ((d & 7) << 4);
        bf16x8 vf = *reinterpret_cast<const bf16x8*>(lv + a);
        Oacc[dt] = MFMA32(vf, pfrag[s], Oacc[dt], 0, 0, 0);
      }
    }

    asm volatile("s_waitcnt vmcnt(4)" ::: "memory");
    __builtin_amdgcn_s_barrier();
    cur = cur + 1 == 3 ? 0 : cur + 1;
  }
#undef STAGE

  // ---- epilogue: O^T regs -> attno[s][h*64+d], normalized ----
  const float rdiv = 1.0f / lsum;
  const int srow = q0 + l31;
  u16* orow = O + (size_t)(b * S + srow) * 1024 + h * 64;
#pragma unroll
  for (int dt = 0; dt < 2; ++dt)
#pragma unroll
    for (int c = 0; c < 4; ++c) {
      float v0 = Oacc[dt][4 * c + 0] * rdiv;
      float v1 = Oacc[dt][4 * c + 1] * rdiv;
      float v2 = Oacc[dt][4 * c + 2] * rdiv;
      float v3 = Oacc[dt][4 * c + 3] * rdiv;
      uint2 pk;
      pk.x = (u32)f2bf(v0) | ((u32)f2bf(v1) << 16);
      pk.y = (u32)f2bf(v2) | ((u32)f2bf(v3) << 16);
      *reinterpret_cast<uint2*>(orow + dt * 32 + c * 8 + hi * 4) = pk;
    }
}

extern "C" void kernel_launch(void* const* d_in, const int* in_sizes, int n_in,
                              void* d_out, int out_size, void* d_ws, size_t ws_size,
                              hipStream_t stream) {
  (void)in_sizes; (void)n_in; (void)out_size; (void)ws_size;
  const float* x = (const float*)d_in[0];
  const float* wqkv = (const float*)d_in[1];
  const float* wout = (const float*)d_in[2];
  const int* pos = (const int*)d_in[3];
  float* out = (float*)d_out;

  char* ws = (char*)d_ws;
  u16* xb     = (u16*)(ws);             // 8 MB   x bf16 [4096][1024]
  u16* wqkvb  = (u16*)(ws + 8388608);   // 6 MB   Wqkv bf16 [3072][1024]
  u16* woutb  = (u16*)(ws + 14680064);  // 2 MB   Wout bf16 [1024][1024]
  u16* qkvb   = (u16*)(ws + 16777216);  // 24 MB  qkv bf16 [4096][3072]
  u16* qro    = (u16*)(ws + 41943040);  // 8 MB   q roped*0.125*log2e
  u16* kro    = (u16*)(ws + 50331648);  // 8 MB   k roped [BH][S][64]
  u16* vt     = (u16*)(ws + 58720256);  // 8 MB   v^T [BH][64][S]
  u16* attno  = (u16*)(ws + 67108864);  // 8 MB   attn out bf16 [4096][1024]
  float2* tab = (float2*)(ws + 75497472); // 512 KB trig table

  cvt_bf16<<<4096, 256, 0, stream>>>(x, xb, 1048576);
  cvt_bf16<<<3072, 256, 0, stream>>>(wqkv, wqkvb, 786432);
  cvt_bf16<<<1024, 256, 0, stream>>>(wout, woutb, 262144);
  build_trig<<<256, 256, 0, stream>>>(pos, tab);
  gemm_bt<true><<<dim3(24, 32), 256, 0, stream>>>(xb, wqkvb, qkvb, 4096, 3072, 1024);
  rope_repack<<<8192, 256, 0, stream>>>(qkvb, tab, qro, kro);
  v_transpose<<<dim3(32, 32), 256, 0, stream>>>(qkvb, vt);
  attn_fwd2<<<512, 256, 0, stream>>>(qro, kro, vt, attno);
  gemm_bt<false><<<dim3(8, 32), 256, 0, stream>>>(attno, woutb, out, 4096, 1024, 1024);
}